// Round 1
// baseline (148.684 us; speedup 1.0000x reference)
//
#include <hip/hip_runtime.h>
#include <hip/hip_bf16.h>
#include <math.h>

// Problem constants (from reference setup_inputs)
constexpr int N_ = 16;
constexpr int K_ = 32768;
constexpr int C_ = 16;
constexpr int M_ = 128;

constexpr int KC = 1024;          // k-chunk per block
constexpr int CHUNKS = K_ / KC;   // 32
constexpr int NCH = CHUNKS * 2;   // 64 partials per (n,m) row (2 halves per chunk)
constexpr int ROWS = N_ * M_;     // 2048

// ---------------------------------------------------------------------------
// Kernel 1: per (n, k-chunk) block. Stage pb chunk into LDS (with per-k
// derived values), then each thread owns one m (lane-major so a wave's 64
// lanes share the k sequence -> broadcast LDS reads) and a k half-slice,
// maintaining a running argmax of IoU. Writes per-(row, chunkhalf) partials.
// ---------------------------------------------------------------------------
__global__ __launch_bounds__(256) void iou_argmax_kernel(
    const float* __restrict__ pred_boxes,
    const float* __restrict__ target,
    float* __restrict__ piou, int* __restrict__ pidx) {
  // LDS: per k (stride 8 floats = 32 B for b128 alignment):
  //   [0]=x1 [1]=y1 [2]=x2+1 [3]=y2+1 [4]=a1
  __shared__ float lds[KC * 8];

  const int chunk = blockIdx.x;
  const int n = blockIdx.y;
  const int k0 = chunk * KC;
  const int tid = threadIdx.x;

  // ---- stage chunk: 1024 k's, 256 threads -> 4 each ----
  for (int j = 0; j < KC / 256; ++j) {
    const int kl = tid + j * 256;
    const float* p = pred_boxes + ((size_t)(n * K_ + k0 + kl)) * 5;
    const float x = p[0];
    const float y = p[1];
    const float w = p[2];
    const float h = p[3];
    const float px2 = w + x;  // ref: pb[...,2] + pb[...,0]
    const float py2 = h + y;
    const float a1 = (px2 - x + 1.0f) * (py2 - y + 1.0f);  // exact ref formula
    float* q = lds + kl * 8;
    q[0] = x;
    q[1] = y;
    q[2] = px2 + 1.0f;
    q[3] = py2 + 1.0f;
    q[4] = a1;
  }
  __syncthreads();

  const int m = tid & (M_ - 1);
  const int half = tid >> 7;  // 0: k in [0,512), 1: k in [512,1024)

  // per-lane target values (tboxes = target[...,1:])
  const float* tg = target + ((size_t)(n * M_ + m)) * 5;
  const float tx1 = tg[1];
  const float ty1 = tg[2];
  const float tx2p1 = tg[3] + 1.0f;
  const float ty2p1 = tg[4] + 1.0f;
  const float a2 = (tg[3] - tg[1] + 1.0f) * (tg[4] - tg[2] + 1.0f);
  const float a2e = a2 + 1e-16f;

  float best = -INFINITY;
  int bk = 0;

  const int ks = half * (KC / 2);
  const int ke = ks + (KC / 2);
#pragma unroll 4
  for (int kl = ks; kl < ke; ++kl) {
    const float4 v = *(const float4*)(lds + kl * 8);  // broadcast b128
    const float a1 = lds[kl * 8 + 4];                 // broadcast b32
    float w = fminf(v.z, tx2p1) - fmaxf(v.x, tx1);
    float h = fminf(v.w, ty2p1) - fmaxf(v.y, ty1);
    w = fmaxf(w, 0.0f);
    h = fmaxf(h, 0.0f);
    const float inter = w * h;
    const float denom = (a1 + a2e) - inter;
    float r = __builtin_amdgcn_rcpf(denom);
    r = r * __builtin_fmaf(-denom, r, 2.0f);  // 1 Newton step -> ~0.5 ulp
    const float iou = inter * r;
    if (iou > best) {  // strict > keeps first occurrence within slice
      best = iou;
      bk = kl;
    }
  }

  const int c = chunk * 2 + half;  // ascending c == ascending k
  const int row = n * M_ + m;
  piou[(size_t)c * ROWS + row] = best;
  pidx[(size_t)c * ROWS + row] = k0 + bk;
}

// ---------------------------------------------------------------------------
// Kernel 2: one block per n (128 threads, one per m). Reduce the 64 partials
// per row (ascending k order, strict > => first-max semantics), gather best
// box/cls, compute per-row loss terms, mask, reduce to per-n sums.
// ws2[n*8 + {0..6}] = {mask, ce, x, y, w, h, conf}
// ---------------------------------------------------------------------------
__global__ __launch_bounds__(128) void row_loss_kernel(
    const float* __restrict__ pred_boxes,
    const float* __restrict__ pred_cls,
    const float* __restrict__ target,
    const float* __restrict__ piou, const int* __restrict__ pidx,
    float* __restrict__ ws2) {
  const int n = blockIdx.x;
  const int m = threadIdx.x;
  const int row = n * M_ + m;

  float best = -INFINITY;
  int bk = 0;
#pragma unroll 8
  for (int c = 0; c < NCH; ++c) {
    const float v = piou[(size_t)c * ROWS + row];
    const int id = pidx[(size_t)c * ROWS + row];
    if (v > best) {
      best = v;
      bk = id;
    }
  }

  const float* tg = target + (size_t)row * 5;
  const float t0 = tg[0], t1 = tg[1], t2 = tg[2], t3 = tg[3], t4 = tg[4];
  const float sum5 = t0 + t1 + t2 + t3 + t4;
  const float mk = (sum5 != 0.0f) ? 1.0f : 0.0f;
  const int bidx = (sum5 != 0.0f) ? bk : 0;

  const float* pb = pred_boxes + ((size_t)(n * K_ + bidx)) * 5;
  const float b0 = pb[0], b1 = pb[1], b2 = pb[2], b3 = pb[3];

  // cross-entropy via log-softmax over C=16
  const float* pc = pred_cls + ((size_t)(n * K_ + bidx)) * C_;
  int tcls = (int)t0;
  tcls = tcls < 0 ? 0 : (tcls >= C_ ? C_ - 1 : tcls);
  float vals[C_];
  float mx = -INFINITY;
#pragma unroll
  for (int c = 0; c < C_; ++c) {
    vals[c] = pc[c];
    mx = fmaxf(mx, vals[c]);
  }
  float se = 0.0f;
#pragma unroll
  for (int c = 0; c < C_; ++c) se += expf(vals[c] - mx);
  const float ce = logf(se) + mx - vals[tcls];

  const float dx = b0 - t1;
  const float dy = b1 - t2;
  const float dw = b2 - (t3 - t1);
  const float dh = b3 - (t4 - t2);

  // conf: conf_idx == 0 => sigmoid(pred_boxes[n,0,4]) for every m
  const float pcf = pred_boxes[(size_t)n * K_ * 5 + 4];
  const float bc = 1.0f / (1.0f + expf(-pcf));
  const float bce = (bc > 0.5f) ? -logf(bc) : -logf(1.0f - bc);

  float acc[7];
  acc[0] = mk;
  acc[1] = mk * ce;
  acc[2] = mk * dx * dx;
  acc[3] = mk * dy * dy;
  acc[4] = mk * dw * dw;
  acc[5] = mk * dh * dh;
  acc[6] = mk * bce;

  // wave(64) shuffle reduce, then combine 2 waves via LDS
  __shared__ float red[2][7];
#pragma unroll
  for (int i = 0; i < 7; ++i) {
    float v = acc[i];
    for (int off = 32; off > 0; off >>= 1) v += __shfl_down(v, off, 64);
    acc[i] = v;
  }
  const int lane = m & 63;
  const int wid = m >> 6;
  if (lane == 0) {
#pragma unroll
    for (int i = 0; i < 7; ++i) red[wid][i] = acc[i];
  }
  __syncthreads();
  if (m == 0) {
#pragma unroll
    for (int i = 0; i < 7; ++i) ws2[n * 8 + i] = red[0][i] + red[1][i];
  }
}

// ---------------------------------------------------------------------------
// Kernel 3: combine 16 per-n partial sums -> 7 output scalars.
// out order: loss, loss_cls, loss_x, loss_y, loss_w, loss_h, loss_conf
// ---------------------------------------------------------------------------
__global__ __launch_bounds__(64) void finalize_kernel(
    const float* __restrict__ ws2, float* __restrict__ out) {
  if (threadIdx.x != 0) return;
  float s[7] = {0, 0, 0, 0, 0, 0, 0};
  for (int n = 0; n < N_; ++n)
#pragma unroll
    for (int i = 0; i < 7; ++i) s[i] += ws2[n * 8 + i];
  const float denom = s[0];
  const float lc = s[1] / denom;
  const float lx = s[2] / denom;
  const float ly = s[3] / denom;
  const float lw = s[4] / denom;
  const float lh = s[5] / denom;
  const float lf = s[6] / denom;
  out[0] = lc + lx + ly + lw + lh + lf;
  out[1] = lc;
  out[2] = lx;
  out[3] = ly;
  out[4] = lw;
  out[5] = lh;
  out[6] = lf;
}

extern "C" void kernel_launch(void* const* d_in, const int* in_sizes, int n_in,
                              void* d_out, int out_size, void* d_ws, size_t ws_size,
                              hipStream_t stream) {
  const float* pred_boxes = (const float*)d_in[0];
  const float* pred_cls = (const float*)d_in[1];
  const float* target = (const float*)d_in[2];
  float* out = (float*)d_out;

  // workspace layout
  float* piou = (float*)d_ws;                          // NCH*ROWS floats (512 KB)
  int* pidx = (int*)(piou + (size_t)NCH * ROWS);       // NCH*ROWS ints  (512 KB)
  float* ws2 = (float*)(pidx + (size_t)NCH * ROWS);    // 16*8 floats

  dim3 g1(CHUNKS, N_);
  iou_argmax_kernel<<<g1, 256, 0, stream>>>(pred_boxes, target, piou, pidx);
  row_loss_kernel<<<N_, 128, 0, stream>>>(pred_boxes, pred_cls, target, piou, pidx, ws2);
  finalize_kernel<<<1, 64, 0, stream>>>(ws2, out);
}

// Round 2
// 130.268 us; speedup vs baseline: 1.1414x; 1.1414x over previous
//
#include <hip/hip_runtime.h>
#include <hip/hip_bf16.h>
#include <math.h>

// Problem constants (from reference setup_inputs)
constexpr int N_ = 16;
constexpr int K_ = 32768;
constexpr int C_ = 16;
constexpr int M_ = 128;

constexpr int KC = 256;           // k-chunk per block (8 KB LDS -> 8 blocks/CU)
constexpr int CHUNKS = K_ / KC;   // 128
constexpr int ROWS = N_ * M_;     // 2048

// ---------------------------------------------------------------------------
// Kernel 1: per (n, k-chunk) block, 256 threads = (m in [0,128)) x (half).
// Stage KC boxes into LDS with derived per-k values; lanes of a wave share the
// k sequence -> broadcast LDS reads. Each thread scans 128 k's; the two
// halves merge through LDS so each row gets ONE partial per chunk.
// Block (0,0) also zeroes the completion counter used by kernel 2.
// ---------------------------------------------------------------------------
__global__ __launch_bounds__(256, 8) void iou_argmax_kernel(
    const float* __restrict__ pred_boxes,
    const float* __restrict__ target,
    float* __restrict__ piou, int* __restrict__ pidx,
    int* __restrict__ counter) {
  // per k (stride 8 floats = 32 B): [0]=x1 [1]=y1 [2]=x2+1 [3]=y2+1 [4]=a1
  __shared__ float lds[KC * 8];
  __shared__ float miou[M_];
  __shared__ int midx[M_];

  const int chunk = blockIdx.x;
  const int n = blockIdx.y;
  const int k0 = chunk * KC;
  const int tid = threadIdx.x;

  if (chunk == 0 && n == 0 && tid == 0) counter[0] = 0;

  // ---- stage chunk: 256 k's, 256 threads -> 1 each ----
  {
    const float* p = pred_boxes + ((size_t)(n * K_ + k0 + tid)) * 5;
    const float x = p[0];
    const float y = p[1];
    const float w = p[2];
    const float h = p[3];
    const float px2 = w + x;  // ref: pb[...,2] + pb[...,0]
    const float py2 = h + y;
    const float a1 = (px2 - x + 1.0f) * (py2 - y + 1.0f);  // exact ref formula
    float* q = lds + tid * 8;
    q[0] = x;
    q[1] = y;
    q[2] = px2 + 1.0f;
    q[3] = py2 + 1.0f;
    q[4] = a1;
  }
  __syncthreads();

  const int m = tid & (M_ - 1);
  const int half = tid >> 7;  // 0: kl in [0,128), 1: kl in [128,256)

  // per-lane target values (tboxes = target[...,1:])
  const float* tg = target + ((size_t)(n * M_ + m)) * 5;
  const float tx1 = tg[1];
  const float ty1 = tg[2];
  const float tx2p1 = tg[3] + 1.0f;
  const float ty2p1 = tg[4] + 1.0f;
  const float a2 = (tg[3] - tg[1] + 1.0f) * (tg[4] - tg[2] + 1.0f);
  const float a2e = a2 + 1e-16f;

  float best = -INFINITY;
  int bk = 0;

  const int ks = half * (KC / 2);
  const int ke = ks + (KC / 2);
#pragma unroll 8
  for (int kl = ks; kl < ke; ++kl) {
    const float4 v = *(const float4*)(lds + kl * 8);  // broadcast b128
    const float a1 = lds[kl * 8 + 4];                 // broadcast b32
    float w = fminf(v.z, tx2p1) - fmaxf(v.x, tx1);
    float h = fminf(v.w, ty2p1) - fmaxf(v.y, ty1);
    w = fmaxf(w, 0.0f);
    h = fmaxf(h, 0.0f);
    const float inter = w * h;
    const float denom = (a1 + a2e) - inter;
    float r = __builtin_amdgcn_rcpf(denom);
    r = r * __builtin_fmaf(-denom, r, 2.0f);  // 1 Newton step -> ~0.5 ulp
    const float iou = inter * r;
    const bool gt = iou > best;  // strict > keeps first occurrence
    best = gt ? iou : best;
    bk = gt ? kl : bk;
  }

  // merge halves: half-1 k's come AFTER half-0 k's -> strict > keeps earliest
  if (half == 1) {
    miou[m] = best;
    midx[m] = k0 + bk;
  }
  __syncthreads();
  if (half == 0) {
    const float o = miou[m];
    const int oi = midx[m];
    const bool gt = o > best;
    const float fb = gt ? o : best;
    const int fi = gt ? oi : (k0 + bk);
    const int row = n * M_ + m;
    piou[(size_t)chunk * ROWS + row] = fb;
    pidx[(size_t)chunk * ROWS + row] = fi;
  }
}

// ---------------------------------------------------------------------------
// Kernel 2: one block per n (128 threads, one per m). Reduce the 128 chunk
// partials per row (ascending k order, strict > => first-max semantics),
// gather best box/cls, compute per-row loss terms, mask, reduce to per-n
// sums in ws2. The LAST block (device-scope atomic counter) finalizes the
// 7 output scalars.
// ws2[n*8 + {0..6}] = {mask, ce, x, y, w, h, conf}
// ---------------------------------------------------------------------------
__global__ __launch_bounds__(128) void row_loss_kernel(
    const float* __restrict__ pred_boxes,
    const float* __restrict__ pred_cls,
    const float* __restrict__ target,
    const float* __restrict__ piou, const int* __restrict__ pidx,
    float* __restrict__ ws2, int* __restrict__ counter,
    float* __restrict__ out) {
  const int n = blockIdx.x;
  const int m = threadIdx.x;
  const int row = n * M_ + m;

  float best = -INFINITY;
  int bk = 0;
#pragma unroll 8
  for (int c = 0; c < CHUNKS; ++c) {
    const float v = piou[(size_t)c * ROWS + row];
    const int id = pidx[(size_t)c * ROWS + row];
    const bool gt = v > best;
    best = gt ? v : best;
    bk = gt ? id : bk;
  }

  const float* tg = target + (size_t)row * 5;
  const float t0 = tg[0], t1 = tg[1], t2 = tg[2], t3 = tg[3], t4 = tg[4];
  const float sum5 = t0 + t1 + t2 + t3 + t4;
  const float mk = (sum5 != 0.0f) ? 1.0f : 0.0f;
  const int bidx = (sum5 != 0.0f) ? bk : 0;

  const float* pb = pred_boxes + ((size_t)(n * K_ + bidx)) * 5;
  const float b0 = pb[0], b1 = pb[1], b2 = pb[2], b3 = pb[3];

  // cross-entropy via log-softmax over C=16
  const float* pc = pred_cls + ((size_t)(n * K_ + bidx)) * C_;
  int tcls = (int)t0;
  tcls = tcls < 0 ? 0 : (tcls >= C_ ? C_ - 1 : tcls);
  float vals[C_];
  float mx = -INFINITY;
#pragma unroll
  for (int c = 0; c < C_; ++c) {
    vals[c] = pc[c];
    mx = fmaxf(mx, vals[c]);
  }
  float se = 0.0f;
#pragma unroll
  for (int c = 0; c < C_; ++c) se += expf(vals[c] - mx);
  const float ce = logf(se) + mx - vals[tcls];

  const float dx = b0 - t1;
  const float dy = b1 - t2;
  const float dw = b2 - (t3 - t1);
  const float dh = b3 - (t4 - t2);

  // conf: conf_idx == 0 => sigmoid(pred_boxes[n,0,4]) for every m
  const float pcf = pred_boxes[(size_t)n * K_ * 5 + 4];
  const float bc = 1.0f / (1.0f + expf(-pcf));
  const float bce = (bc > 0.5f) ? -logf(bc) : -logf(1.0f - bc);

  float acc[7];
  acc[0] = mk;
  acc[1] = mk * ce;
  acc[2] = mk * dx * dx;
  acc[3] = mk * dy * dy;
  acc[4] = mk * dw * dw;
  acc[5] = mk * dh * dh;
  acc[6] = mk * bce;

  // wave(64) shuffle reduce, then combine 2 waves via LDS
  __shared__ float red[2][7];
#pragma unroll
  for (int i = 0; i < 7; ++i) {
    float v = acc[i];
    for (int off = 32; off > 0; off >>= 1) v += __shfl_down(v, off, 64);
    acc[i] = v;
  }
  const int lane = m & 63;
  const int wid = m >> 6;
  if (lane == 0) {
#pragma unroll
    for (int i = 0; i < 7; ++i) red[wid][i] = acc[i];
  }
  __syncthreads();

  __shared__ int s_last;
  if (m == 0) {
#pragma unroll
    for (int i = 0; i < 7; ++i) ws2[n * 8 + i] = red[0][i] + red[1][i];
    __threadfence();  // make ws2 visible device-wide before signaling
    const int old = atomicAdd(counter, 1);
    s_last = (old == N_ - 1) ? 1 : 0;
  }
  __syncthreads();

  if (s_last && m == 0) {
    __threadfence();  // acquire side
    float s[7] = {0, 0, 0, 0, 0, 0, 0};
    for (int nn = 0; nn < N_; ++nn)
#pragma unroll
      for (int i = 0; i < 7; ++i) s[i] += ws2[nn * 8 + i];
    const float denom = s[0];
    const float lc = s[1] / denom;
    const float lx = s[2] / denom;
    const float ly = s[3] / denom;
    const float lw = s[4] / denom;
    const float lh = s[5] / denom;
    const float lf = s[6] / denom;
    out[0] = lc + lx + ly + lw + lh + lf;
    out[1] = lc;
    out[2] = lx;
    out[3] = ly;
    out[4] = lw;
    out[5] = lh;
    out[6] = lf;
  }
}

extern "C" void kernel_launch(void* const* d_in, const int* in_sizes, int n_in,
                              void* d_out, int out_size, void* d_ws, size_t ws_size,
                              hipStream_t stream) {
  const float* pred_boxes = (const float*)d_in[0];
  const float* pred_cls = (const float*)d_in[1];
  const float* target = (const float*)d_in[2];
  float* out = (float*)d_out;

  // workspace layout
  float* piou = (float*)d_ws;                            // CHUNKS*ROWS floats (1 MB)
  int* pidx = (int*)(piou + (size_t)CHUNKS * ROWS);      // CHUNKS*ROWS ints  (1 MB)
  float* ws2 = (float*)(pidx + (size_t)CHUNKS * ROWS);   // 16*8 floats
  int* counter = (int*)(ws2 + N_ * 8);                   // 1 int

  dim3 g1(CHUNKS, N_);
  iou_argmax_kernel<<<g1, 256, 0, stream>>>(pred_boxes, target, piou, pidx, counter);
  row_loss_kernel<<<N_, 128, 0, stream>>>(pred_boxes, pred_cls, target, piou, pidx,
                                          ws2, counter, out);
}